// Round 10
// baseline (676.584 us; speedup 1.0000x reference)
//
#include <hip/hip_runtime.h>
#include <hip/hip_cooperative_groups.h>

namespace cg = cooperative_groups;

typedef unsigned short u16;
typedef __attribute__((ext_vector_type(8))) short bf8;   // 8 bf16 (4 VGPRs)
typedef __attribute__((ext_vector_type(4))) float f4;    // MFMA C/D frag
typedef __attribute__((ext_vector_type(4))) int i4;

#define NB  30
#define BG  2048
#define EPG 240
#define NEg (BG*EPG)
#define SA  264     // A row stride (shorts)
#define SS  40      // S row stride
#define SL  264     // latent row stride (heads)

// workspace offsets (bytes)
#define WOFF_WT    0                         // W_mp^T bf16 [3][256][512]
#define WOFF_WAGG  786432                    // W_agg^T bf16 [256][1024]
#define WOFF_WMU   (786432+524288)           // [256][256] bf16
#define WOFF_WVAR  (786432+524288+131072)
#define WOFF_TAB   (786432+524288+262144)    // fp32 tables: 12032 floats
#define WOFF_G     (WOFF_TAB + 48128)        // g bf16 [2048][1024]
#define WOFF_FLAG  (WOFF_G + 4194304)        // 2 ints

// LDS pool layout (bytes)
#define POOL_SZ    27648
#define L_AHI      0          // short[32*264] = 16896
#define L_SHI      16896      // short[32*40]  = 2560
#define L_SLO      19456      // 2560
#define L_CNTC     22016      // int[1024] = 4096
#define L_CNTN     26112      // int[32] = 128
#define L_GEO      26240      // float[150] = 600
#define L_SEM      26840      // int[30] = 120
// head overlay: Lhi@0 (8448), Llo@8448 (8448)

struct KP {
    const float* geometry; const void* sem; const void* edge;
    const float *W_geo, *b_geo, *emb, *W_lot, *b_lot;
    const float *Wmp1, *bmp1, *Wmp2, *bmp2, *Wmp3, *bmp3;
    const float *Wagg, *bagg, *Wmu, *bmu, *Wvar, *bvar;
    char* ws; u16* G; int* flags; float* out;
};

__device__ __forceinline__ float us2f(u16 u) {
    union { unsigned int i; float f; } v; v.i = ((unsigned int)u) << 16; return v.f;
}
__device__ __forceinline__ u16 f2us(float f) {
    union { float f; unsigned int u; } v; v.f = f;
    unsigned int u = v.u;
    return (u16)((u + 0x7FFFu + ((u >> 16) & 1u)) >> 16);   // RNE
}
__device__ __forceinline__ int ldidx(const void* p, long long i, int i64) {
    return i64 ? (int)((const long long*)p)[i] : ((const int*)p)[i];
}

// ---------------------------------------------------------------------------
__device__ void prep_dev(int b, int t, char* pool, const KP& p)
{
    if (b == 209) {                    // probe
        if (t == 0) {
            const int* e32 = (const int*)p.edge;
            int zc = 0;
            for (int j = 1; j <= 31; j += 2) if (e32[j] == 0) zc++;
            const int i64 = (zc == 16) ? 1 : 0;
            p.flags[0] = i64;
            const int a = ldidx(p.sem, 61439, i64);
            p.flags[1] = (a > 10) ? 1 : 0;
        }
        return;
    }
    if (b >= 192) {                    // tables (exact fp32 algebra)
        float* tab = (float*)(p.ws + WOFF_TAB);
        const int d = t, b2 = b - 192;
        if (b2 < 5) {
            float a = 0.f;
            for (int k = 0; k < 256; ++k)
                a = fmaf(p.W_geo[b2*256 + k], p.W_lot[k*256 + d], a);
            tab[b2*256 + d] = a;
        } else if (b2 < 16) {
            const int s = b2 - 5;
            float a = 0.f;
            for (int k = 0; k < 256; ++k)
                a = fmaf(p.emb[s*256 + k], p.W_lot[(256 + k)*256 + d], a);
            tab[1536 + s*256 + d] = a;
        } else {
            float a = p.b_lot[d];
            for (int k = 0; k < 256; ++k)
                a = fmaf(p.b_geo[k], p.W_lot[k*256 + d], a);
            tab[1280 + d] = a;
            for (int pp = 0; pp < NB; ++pp)
                tab[4352 + pp*256 + d] = p.W_lot[(512 + pp)*256 + d];
        }
        return;
    }

    // 64x64 tile transpose: W[K][256] fp32 -> Wt[256][K] bf16
    short* tile = (short*)pool;        // 64*65 shorts = 8320 B
    const float* W; u16* Wt; int K, bk, bn;
    if (b < 96)       { const int r = b/32, tt = b%32;
                        W = (r==0)?p.Wmp1:((r==1)?p.Wmp2:p.Wmp3);
                        Wt = (u16*)(p.ws + WOFF_WT) + (size_t)r*256*512;
                        K = 512;  bk = tt/4;  bn = tt%4; }
    else if (b < 160) { const int tt = b-96;
                        W = p.Wagg; Wt = (u16*)(p.ws + WOFF_WAGG);
                        K = 1024; bk = tt/4;  bn = tt%4; }
    else if (b < 176) { const int tt = b-160;
                        W = p.Wmu;  Wt = (u16*)(p.ws + WOFF_WMU);
                        K = 256;  bk = tt/4;  bn = tt%4; }
    else              { const int tt = b-176;
                        W = p.Wvar; Wt = (u16*)(p.ws + WOFF_WVAR);
                        K = 256;  bk = tt/4;  bn = tt%4; }

    const int r = t >> 6, c = t & 63;
    const int k0 = bk*64, n0 = bn*64;
    #pragma unroll
    for (int i = 0; i < 16; ++i) {
        const int kk = r + i*4;
        tile[kk*65 + c] = (short)f2us(W[(size_t)(k0 + kk)*256 + n0 + c]);
    }
    __syncthreads();
    #pragma unroll
    for (int i = 0; i < 16; ++i) {
        const int nn = r + i*4;
        Wt[(size_t)(n0 + nn)*K + k0 + c] = (u16)tile[c*65 + nn];
    }
}

// ---------------------------------------------------------------------------
__device__ void graph_dev(int g, int tid, char* pool, const KP& p)
{
    short* Ahi  = (short*)(pool + L_AHI);
    short* Shi  = (short*)(pool + L_SHI);
    short* Slo  = (short*)(pool + L_SLO);
    int*   cntC = (int*)(pool + L_CNTC);
    int*   cntN = (int*)(pool + L_CNTN);
    float* geo_l= (float*)(pool + L_GEO);
    int*   sem_l= (int*)(pool + L_SEM);

    const int wave = tid >> 6, lane = tid & 63;
    const int l16  = lane & 15, quad = lane >> 4;

    const int i64 = p.flags[0];
    const void* semantic = p.flags[1] ? p.edge : p.sem;  // never actually swapped (flags[1]==0)
    const u16* WtAll = (const u16*)(p.ws + WOFF_WT);
    const float* tab = (const float*)(p.ws + WOFF_TAB);
    u16* G = p.G;

    // ---- zero / stage ----
    {
        i4 z = {0, 0, 0, 0};
        if (tid < 66) ((i4*)&Ahi[30*SA])[tid] = z;            // rows 30,31
        if (tid < 160) { ((i4*)Shi)[tid] = z; ((i4*)Slo)[tid] = z; }
        ((i4*)cntC)[tid] = z;
        if (tid < 32) cntN[tid] = 0;
        if (tid < NB*5) geo_l[tid] = p.geometry[(size_t)g*NB*5 + tid];
        if (tid < NB)   sem_l[tid] = ldidx(semantic, g*NB + tid, i64);
    }
    __syncthreads();

    // ---- edge counts ----
    if (tid < EPG) {
        const long long e = (long long)g*EPG + tid;
        const int s  = ldidx(p.edge, e,                  i64) - g*NB;
        const int dd = ldidx(p.edge, (long long)NEg + e, i64) - g*NB;
        atomicAdd(&cntC[dd*32 + s], 1);
        atomicAdd(&cntN[dd], 1);
    }
    __syncthreads();

    // ---- S = cnt_nm / cnt_n, exact hi/lo split ----
    for (int i = tid; i < 960; i += 256) {
        const int n = i >> 5, m = i & 31;
        const int c = cntC[n*32 + m], cn = cntN[n];
        const float v = (cn > 0) ? (float)c / (float)cn : 0.f;
        const u16 hi = f2us(v);
        Shi[n*SS + m] = (short)hi;
        Slo[n*SS + m] = (short)f2us(v - us2f(hi));
    }

    // ---- encoder via exact tables; thread = col d ----
    {
        const int d = tid;
        const float m0 = tab[0*256+d], m1 = tab[1*256+d], m2 = tab[2*256+d],
                    m3 = tab[3*256+d], m4 = tab[4*256+d];
        const float cD = tab[1280 + d];
        float gmax = 0.f;
        for (int n = 0; n < NB; ++n) {
            const int s = sem_l[n];
            float a = cD + tab[1536 + s*256 + d] + tab[4352 + n*256 + d];
            a = fmaf(geo_l[n*5+0], m0, a); a = fmaf(geo_l[n*5+1], m1, a);
            a = fmaf(geo_l[n*5+2], m2, a); a = fmaf(geo_l[n*5+3], m3, a);
            a = fmaf(geo_l[n*5+4], m4, a);
            const float v = fmaxf(a, 0.f);
            Ahi[n*SA + d] = (short)f2us(v);
            gmax = fmaxf(gmax, v);
        }
        G[(size_t)g*1024 + d] = f2us(gmax);   // g0
    }
    __syncthreads();

    // ---- per-lane row mask ----
    unsigned rmask = 0;
    #pragma unroll
    for (int mt = 0; mt < 2; ++mt)
        #pragma unroll
        for (int i = 0; i < 4; ++i) {
            const int row = mt*16 + quad*4 + i;
            if (row < NB && cntN[row] > 0) rmask |= 1u << (mt*4 + i);
        }

    // S fragments (constant across rounds)
    bf8 sh[2], sl[2];
    #pragma unroll
    for (int mo = 0; mo < 2; ++mo) {
        sh[mo] = *(const bf8*)&Shi[(mo*16 + l16)*SS + quad*8];
        sl[mo] = *(const bf8*)&Slo[(mo*16 + l16)*SS + quad*8];
    }
    const int srcbase = ((quad & 1) << 5) | l16;
    const int mtsel   = quad >> 1;

    // ---- 3 message-passing rounds ----
    for (int r = 0; r < 3; ++r) {
        const u16* Wt = WtAll + ((size_t)r*256 + wave*64)*512;

        f4 C1[2][4], P[2][4];
        #pragma unroll
        for (int mt = 0; mt < 2; ++mt)
            #pragma unroll
            for (int nt = 0; nt < 4; ++nt) {
                C1[mt][nt] = (f4){0.f, 0.f, 0.f, 0.f};
                P [mt][nt] = (f4){0.f, 0.f, 0.f, 0.f};
            }

        #pragma unroll
        for (int kt = 0; kt < 8; ++kt) {
            bf8 ah[2];
            #pragma unroll
            for (int mt = 0; mt < 2; ++mt)
                ah[mt] = *(const bf8*)&Ahi[(mt*16 + l16)*SA + kt*32 + quad*8];
            #pragma unroll
            for (int nt = 0; nt < 4; ++nt) {
                const u16* wrow = Wt + (size_t)(nt*16 + l16)*512 + kt*32 + quad*8;
                const bf8 bt = *(const bf8*)wrow;
                const bf8 bb = *(const bf8*)(wrow + 256);
                #pragma unroll
                for (int mt = 0; mt < 2; ++mt) {
                    C1[mt][nt] = __builtin_amdgcn_mfma_f32_16x16x32_bf16(ah[mt], bt, C1[mt][nt], 0, 0, 0);
                    P [mt][nt] = __builtin_amdgcn_mfma_f32_16x16x32_bf16(ah[mt], bb, P [mt][nt], 0, 0, 0);
                }
            }
        }

        // pack P to bf16 pairs
        unsigned pk[2][4][2];
        #pragma unroll
        for (int mt = 0; mt < 2; ++mt)
            #pragma unroll
            for (int nt = 0; nt < 4; ++nt) {
                pk[mt][nt][0] = (unsigned)f2us(P[mt][nt][0]) | ((unsigned)f2us(P[mt][nt][1]) << 16);
                pk[mt][nt][1] = (unsigned)f2us(P[mt][nt][2]) | ((unsigned)f2us(P[mt][nt][3]) << 16);
            }

        // C1 += S @ P (B-frags in-register via shfl)
        #pragma unroll
        for (int nt = 0; nt < 4; ++nt) {
            union { bf8 v; unsigned u[4]; } bf_;
            #pragma unroll
            for (int t2 = 0; t2 < 4; ++t2) {
                const int src = srcbase + ((t2 >> 1) << 4);
                const unsigned v0 = __shfl(pk[0][nt][t2 & 1], src, 64);
                const unsigned v1 = __shfl(pk[1][nt][t2 & 1], src, 64);
                bf_.u[t2] = mtsel ? v1 : v0;
            }
            #pragma unroll
            for (int mo = 0; mo < 2; ++mo) {
                C1[mo][nt] = __builtin_amdgcn_mfma_f32_16x16x32_bf16(sh[mo], bf_.v, C1[mo][nt], 0, 0, 0);
                C1[mo][nt] = __builtin_amdgcn_mfma_f32_16x16x32_bf16(sl[mo], bf_.v, C1[mo][nt], 0, 0, 0);
            }
        }
        __syncthreads();

        // epilogue
        const float* br = (r == 0) ? p.bmp1 : ((r == 1) ? p.bmp2 : p.bmp3);
        #pragma unroll
        for (int nt = 0; nt < 4; ++nt) {
            const int col = wave*64 + nt*16 + l16;
            const float bias = br[col];
            float cmax = 0.f;
            #pragma unroll
            for (int mt = 0; mt < 2; ++mt)
                #pragma unroll
                for (int i = 0; i < 4; ++i) {
                    const int row = mt*16 + quad*4 + i;
                    float v = fmaxf(C1[mt][nt][i] + bias, 0.f);
                    if (!((rmask >> (mt*4 + i)) & 1u)) v = 0.f;
                    Ahi[row*SA + col] = (short)f2us(v);
                    cmax = fmaxf(cmax, v);
                }
            cmax = fmaxf(cmax, __shfl_xor(cmax, 16, 64));
            cmax = fmaxf(cmax, __shfl_xor(cmax, 32, 64));
            if (quad == 0)
                G[(size_t)g*1024 + (r+1)*256 + col] = f2us(cmax);
        }
        __syncthreads();
    }
}

// ---------------------------------------------------------------------------
// Head: block B handles 8 graphs (M=8 via duplicated rows).
// ---------------------------------------------------------------------------
__device__ void head_dev(int B, int tid, char* pool, const KP& p)
{
    short* Lhi = (short*)pool;          // 16*SL shorts = 8448 B
    short* Llo = (short*)(pool + 8448);

    const int wave = tid >> 6, lane = tid & 63;
    const int l16  = lane & 15, quad = lane >> 4;
    const int g0   = B * 8;
    const u16* G   = p.G;

    const u16* WtA = (const u16*)(p.ws + WOFF_WAGG);
    const u16* WtM = (const u16*)(p.ws + WOFF_WMU);
    const u16* WtV = (const u16*)(p.ws + WOFF_WVAR);

    // GEMM1: latent[8][256] = G[8][1024] @ Wagg  (A rows duplicated to 16)
    f4 acc[4];
    #pragma unroll
    for (int nt = 0; nt < 4; ++nt) acc[nt] = (f4){0.f, 0.f, 0.f, 0.f};

    #pragma unroll 4
    for (int kt = 0; kt < 32; ++kt) {
        const bf8 ah = *(const bf8*)&G[(size_t)(g0 + (l16 & 7))*1024 + kt*32 + quad*8];
        #pragma unroll
        for (int nt = 0; nt < 4; ++nt) {
            const bf8 b = *(const bf8*)&WtA[(size_t)(wave*64 + nt*16 + l16)*1024 + kt*32 + quad*8];
            acc[nt] = __builtin_amdgcn_mfma_f32_16x16x32_bf16(ah, b, acc[nt], 0, 0, 0);
        }
    }
    #pragma unroll
    for (int nt = 0; nt < 4; ++nt) {
        const int col = wave*64 + nt*16 + l16;
        const float bias = p.bagg[col];
        #pragma unroll
        for (int i = 0; i < 4; ++i) {
            const int row = quad*4 + i;     // 0..15; rows 8-15 are duplicates
            const float v = acc[nt][i] + bias;
            const u16 hi = f2us(v);
            Lhi[row*SL + col] = (short)hi;
            Llo[row*SL + col] = (short)f2us(v - us2f(hi));
        }
    }
    __syncthreads();

    // GEMM2: mu / log_var
    f4 am[4], av[4];
    #pragma unroll
    for (int nt = 0; nt < 4; ++nt) {
        am[nt] = (f4){0.f, 0.f, 0.f, 0.f};
        av[nt] = (f4){0.f, 0.f, 0.f, 0.f};
    }
    #pragma unroll
    for (int kt = 0; kt < 8; ++kt) {
        const bf8 ah = *(const bf8*)&Lhi[l16*SL + kt*32 + quad*8];
        const bf8 al = *(const bf8*)&Llo[l16*SL + kt*32 + quad*8];
        #pragma unroll
        for (int nt = 0; nt < 4; ++nt) {
            const bf8 bm_ = *(const bf8*)&WtM[(wave*64 + nt*16 + l16)*256 + kt*32 + quad*8];
            const bf8 bv_ = *(const bf8*)&WtV[(wave*64 + nt*16 + l16)*256 + kt*32 + quad*8];
            am[nt] = __builtin_amdgcn_mfma_f32_16x16x32_bf16(ah, bm_, am[nt], 0, 0, 0);
            am[nt] = __builtin_amdgcn_mfma_f32_16x16x32_bf16(al, bm_, am[nt], 0, 0, 0);
            av[nt] = __builtin_amdgcn_mfma_f32_16x16x32_bf16(ah, bv_, av[nt], 0, 0, 0);
            av[nt] = __builtin_amdgcn_mfma_f32_16x16x32_bf16(al, bv_, av[nt], 0, 0, 0);
        }
    }
    #pragma unroll
    for (int nt = 0; nt < 4; ++nt) {
        const int col = wave*64 + nt*16 + l16;
        const float b1 = p.bmu[col], b2 = p.bvar[col];
        #pragma unroll
        for (int i = 0; i < 4; ++i) {
            const int r = quad*4 + i;
            if (r < 8) {
                const int row = g0 + r;
                p.out[(size_t)row*256 + col]          = am[nt][i] + b1;
                p.out[524288 + (size_t)row*256 + col] = av[nt][i] + b2;
            }
        }
    }
}

// ---------------------------------------------------------------------------
__global__ __launch_bounds__(256, 4) void mega_kernel(KP p)
{
    __shared__ __align__(16) char pool[POOL_SZ];
    const int b = blockIdx.x, t = threadIdx.x;
    if (b < 210) prep_dev(b, t, pool, p);
    cg::this_grid().sync();
    graph_dev(2*b,     t, pool, p);
    __syncthreads();
    graph_dev(2*b + 1, t, pool, p);
    cg::this_grid().sync();
    if (b < 256) head_dev(b, t, pool, p);
}

// fallback (classic 3-launch) versions
__global__ __launch_bounds__(256, 4) void prep_k(KP p) {
    __shared__ __align__(16) char pool[POOL_SZ];
    prep_dev(blockIdx.x, threadIdx.x, pool, p);
}
__global__ __launch_bounds__(256, 4) void graph_k(KP p) {
    __shared__ __align__(16) char pool[POOL_SZ];
    graph_dev(2*blockIdx.x, threadIdx.x, pool, p);
    __syncthreads();
    graph_dev(2*blockIdx.x + 1, threadIdx.x, pool, p);
}
__global__ __launch_bounds__(256, 4) void head_k(KP p) {
    __shared__ __align__(16) char pool[POOL_SZ];
    head_dev(blockIdx.x, threadIdx.x, pool, p);
}

extern "C" void kernel_launch(void* const* d_in, const int* in_sizes, int n_in,
                              void* d_out, int out_size, void* d_ws, size_t ws_size,
                              hipStream_t stream)
{
    KP p;
    p.geometry = (const float*)d_in[0];
    p.sem      = d_in[1];
    p.edge     = d_in[2];
    // d_in[3] = batch (unused)
    p.W_geo = (const float*)d_in[4];
    p.b_geo = (const float*)d_in[5];
    p.emb   = (const float*)d_in[6];
    p.W_lot = (const float*)d_in[7];
    p.b_lot = (const float*)d_in[8];
    p.Wmp1  = (const float*)d_in[9];
    p.bmp1  = (const float*)d_in[10];
    p.Wmp2  = (const float*)d_in[11];
    p.bmp2  = (const float*)d_in[12];
    p.Wmp3  = (const float*)d_in[13];
    p.bmp3  = (const float*)d_in[14];
    p.Wagg  = (const float*)d_in[15];
    p.bagg  = (const float*)d_in[16];
    p.Wmu   = (const float*)d_in[17];
    p.bmu   = (const float*)d_in[18];
    p.Wvar  = (const float*)d_in[19];
    p.bvar  = (const float*)d_in[20];
    p.ws    = (char*)d_ws;
    p.flags = (int*)((char*)d_ws + WOFF_FLAG);
    p.G     = (u16*)((char*)d_ws + WOFF_G);
    p.out   = (float*)d_out;

    void* kp[] = { &p };
    hipError_t err = hipLaunchCooperativeKernel((const void*)mega_kernel,
                                                dim3(1024), dim3(256), kp, 0, stream);
    if (err != hipSuccess) {
        (void)hipGetLastError();   // clear sticky error
        prep_k <<<210,  256, 0, stream>>>(p);
        graph_k<<<1024, 256, 0, stream>>>(p);
        head_k <<<256,  256, 0, stream>>>(p);
    }
}

// Round 11
// 315.891 us; speedup vs baseline: 2.1418x; 2.1418x over previous
//
#include <hip/hip_runtime.h>

typedef unsigned short u16;
typedef unsigned int u32;
typedef __attribute__((ext_vector_type(8))) short bf8;   // 8 bf16 (4 VGPRs)
typedef __attribute__((ext_vector_type(4))) float f4;    // MFMA C/D frag
typedef __attribute__((ext_vector_type(4))) int i4;

#define NB  30
#define BG  2048
#define EPG 240
#define NEg (BG*EPG)
#define SA  260     // A row stride (shorts): 130 dw -> 2*row mod 32, uniform 2-way
#define SS  40      // S row stride
#define SL  264     // latent row stride (heads)
#define SG  1032    // head G-stage row stride (shorts)

// workspace offsets (bytes). W tensors stored fragment-major (swizzled):
// chunk(wave,ktf,nt) = ((wave*(K/32)+ktf)*4+nt)*512 u16, elem = lane*8+j,
// value = W^T[wave*64+nt*16+(lane&15)][ktf*32+(lane>>4)*8+j]
#define WOFF_WT    0                         // [3][256][512] bf16
#define WOFF_WAGG  786432                    // [256][1024] bf16
#define WOFF_WMU   (786432+524288)           // [256][256] bf16
#define WOFF_WVAR  (786432+524288+131072)
#define WOFF_TAB   (786432+524288+262144)    // fp32 tables: 12032 floats
#define WOFF_G     (WOFF_TAB + 48128)        // g bf16 [2048][1024]
#define WOFF_FLAG  (WOFF_G + 4194304)        // 2 ints

__device__ __forceinline__ float us2f(u16 u) {
    union { u32 i; float f; } v; v.i = ((u32)u) << 16; return v.f;
}
__device__ __forceinline__ u16 f2us(float f) {
    union { float f; u32 u; } v; v.f = f;
    u32 u = v.u;
    return (u16)((u + 0x7FFFu + ((u >> 16) & 1u)) >> 16);   // RNE
}
__device__ __forceinline__ int ldidx(const void* p, long long i, int i64) {
    return i64 ? (int)((const long long*)p)[i] : ((const int*)p)[i];
}

// ---------------------------------------------------------------------------
// Prep (210 blocks): 64x64 tile loads -> swizzled fragment-major bf16 writes,
// fp32 encoder tables (192..208), dtype probe (209).
// ---------------------------------------------------------------------------
__global__ __launch_bounds__(256) void prep_kernel(
    const float* __restrict__ Wmp1, const float* __restrict__ Wmp2,
    const float* __restrict__ Wmp3, const float* __restrict__ Wagg,
    const float* __restrict__ Wmu,  const float* __restrict__ Wvar,
    const float* __restrict__ W_geo, const float* __restrict__ b_geo,
    const float* __restrict__ emb,   const float* __restrict__ W_lot,
    const float* __restrict__ b_lot,
    const void* __restrict__ edge,  const void* __restrict__ semA,
    char* __restrict__ ws, int* __restrict__ flags)
{
    const int t = threadIdx.x;
    const int b = blockIdx.x;

    if (b == 209) {                    // probe
        if (t == 0) {
            const int* e32 = (const int*)edge;
            int zc = 0;
            for (int j = 1; j <= 31; j += 2) if (e32[j] == 0) zc++;
            flags[0] = (zc == 16) ? 1 : 0;
            flags[1] = 0;
        }
        return;
    }

    if (b >= 192) {                    // tables (exact fp32 algebra)
        float* tab = (float*)(ws + WOFF_TAB);
        const int d = t, b2 = b - 192;
        if (b2 < 5) {
            float a = 0.f;
            #pragma unroll 8
            for (int k = 0; k < 256; ++k)
                a = fmaf(W_geo[b2*256 + k], W_lot[k*256 + d], a);
            tab[b2*256 + d] = a;
        } else if (b2 < 16) {
            const int s = b2 - 5;
            float a = 0.f;
            #pragma unroll 8
            for (int k = 0; k < 256; ++k)
                a = fmaf(emb[s*256 + k], W_lot[(256 + k)*256 + d], a);
            tab[1536 + s*256 + d] = a;
        } else {
            float a = b_lot[d];
            #pragma unroll 8
            for (int k = 0; k < 256; ++k)
                a = fmaf(b_geo[k], W_lot[k*256 + d], a);
            tab[1280 + d] = a;
            for (int p = 0; p < NB; ++p)
                tab[4352 + p*256 + d] = W_lot[(512 + p)*256 + d];
        }
        return;
    }

    // 64x64 tile: W[K][256] fp32 -> swizzled bf16 chunks
    __shared__ short tile[64 * 65];
    const float* W; u16* Wt; int K32, bk, bn;
    if (b < 96)       { const int r = b/32, tt = b%32;
                        W = (r==0)?Wmp1:((r==1)?Wmp2:Wmp3);
                        Wt = (u16*)(ws + WOFF_WT) + (size_t)r*256*512;
                        K32 = 16;  bk = tt/4;  bn = tt%4; }
    else if (b < 160) { const int tt = b-96;
                        W = Wagg; Wt = (u16*)(ws + WOFF_WAGG);
                        K32 = 32; bk = tt/4;  bn = tt%4; }
    else if (b < 176) { const int tt = b-160;
                        W = Wmu;  Wt = (u16*)(ws + WOFF_WMU);
                        K32 = 8;  bk = tt/4;  bn = tt%4; }
    else              { const int tt = b-176;
                        W = Wvar; Wt = (u16*)(ws + WOFF_WVAR);
                        K32 = 8;  bk = tt/4;  bn = tt%4; }

    const int r = t >> 6, c = t & 63;
    const int k0 = bk*64, n0 = bn*64;
    #pragma unroll
    for (int i = 0; i < 16; ++i) {
        const int kk = r + i*4;
        tile[kk*65 + c] = (short)f2us(W[(size_t)(k0 + kk)*256 + n0 + c]);
    }
    __syncthreads();

    // write 8 chunks (dk x nt), each 1 KB contiguous
    const int lane = t >> 2;
    const int j0   = (t & 3) * 2;
    const int quad = lane >> 4, l16 = lane & 15;
    #pragma unroll
    for (int dk = 0; dk < 2; ++dk) {
        const int ktf = bk*2 + dk;
        #pragma unroll
        for (int nt = 0; nt < 4; ++nt) {
            const int chunk = (bn*K32 + ktf)*4 + nt;
            u32* dst = (u32*)(Wt + (size_t)chunk*512);
            const int kl = dk*32 + quad*8 + j0;
            const int nl = nt*16 + l16;
            const u32 v = (u32)(u16)tile[kl*65 + nl] |
                          ((u32)(u16)tile[(kl+1)*65 + nl] << 16);
            dst[t] = v;
        }
    }
}

// ---------------------------------------------------------------------------
// Graph kernel: one block per graph, 4 waves. W reads fully coalesced
// (fragment-major). cntC overlays Ahi rows 0..7 (barrier-separated).
// ---------------------------------------------------------------------------
__global__ __launch_bounds__(256, 5) void graph_kernel(
    const float* __restrict__ geometry,
    const void* __restrict__ semantic,
    const void* __restrict__ edge_index,
    const float* __restrict__ bmp1, const float* __restrict__ bmp2,
    const float* __restrict__ bmp3,
    const char* __restrict__ ws, u16* __restrict__ G,
    const int* __restrict__ flags)
{
    __shared__ __align__(16) short Ahi[32*SA];   // 16640 B (rows 0..7 alias cntC)
    __shared__ __align__(16) short Shi[32*SS];   // 2560 B
    __shared__ __align__(16) short Slo[32*SS];   // 2560 B
    __shared__ int   cntN[32];
    __shared__ float geo_l[NB*5];
    __shared__ int   sem_l[NB];

    int* cntC = (int*)Ahi;                       // 4096 B overlay

    const int tid  = threadIdx.x;
    const int g    = blockIdx.x;
    const int wave = tid >> 6, lane = tid & 63;
    const int l16  = lane & 15, quad = lane >> 4;

    const int i64 = flags[0];
    const u16* WtAll = (const u16*)(ws + WOFF_WT);
    const float* tab = (const float*)(ws + WOFF_TAB);

    // ---- zero / stage ----
    {
        i4 z = {0, 0, 0, 0};
        ((i4*)cntC)[tid] = z;                                 // 4096 B
        if (tid < 65) ((i4*)&Ahi[30*SA])[tid] = z;            // rows 30,31 (1040 B)
        if (tid < 160) { ((i4*)Shi)[tid] = z; ((i4*)Slo)[tid] = z; }
        if (tid < 32) cntN[tid] = 0;
        if (tid < NB*5) geo_l[tid] = geometry[(size_t)g*NB*5 + tid];
        if (tid < NB)   sem_l[tid] = ldidx(semantic, g*NB + tid, i64);
    }
    __syncthreads();

    // ---- edge counts ----
    if (tid < EPG) {
        const long long e = (long long)g*EPG + tid;
        const int s  = ldidx(edge_index, e,                  i64) - g*NB;
        const int dd = ldidx(edge_index, (long long)NEg + e, i64) - g*NB;
        atomicAdd(&cntC[dd*32 + s], 1);
        atomicAdd(&cntN[dd], 1);
    }
    __syncthreads();

    // ---- S = cnt_nm / cnt_n, exact hi/lo split ----
    for (int i = tid; i < 960; i += 256) {
        const int n = i >> 5, m = i & 31;
        const int c = cntC[n*32 + m], cn = cntN[n];
        const float v = (cn > 0) ? (float)c / (float)cn : 0.f;
        const u16 hi = f2us(v);
        Shi[n*SS + m] = (short)hi;
        Slo[n*SS + m] = (short)f2us(v - us2f(hi));
    }
    __syncthreads();   // cntC reads done before encoder overwrites rows 0..7

    // ---- encoder via exact tables; thread = col d ----
    {
        const int d = tid;
        const float m0 = tab[0*256+d], m1 = tab[1*256+d], m2 = tab[2*256+d],
                    m3 = tab[3*256+d], m4 = tab[4*256+d];
        const float cD = tab[1280 + d];
        float gmax = 0.f;
        for (int n = 0; n < NB; ++n) {
            const int s = sem_l[n];
            float a = cD + tab[1536 + s*256 + d] + tab[4352 + n*256 + d];
            a = fmaf(geo_l[n*5+0], m0, a); a = fmaf(geo_l[n*5+1], m1, a);
            a = fmaf(geo_l[n*5+2], m2, a); a = fmaf(geo_l[n*5+3], m3, a);
            a = fmaf(geo_l[n*5+4], m4, a);
            const float v = fmaxf(a, 0.f);
            Ahi[n*SA + d] = (short)f2us(v);
            gmax = fmaxf(gmax, v);
        }
        G[(size_t)g*1024 + d] = f2us(gmax);   // g0
    }
    __syncthreads();

    // ---- per-lane row mask ----
    unsigned rmask = 0;
    #pragma unroll
    for (int mt = 0; mt < 2; ++mt)
        #pragma unroll
        for (int i = 0; i < 4; ++i) {
            const int row = mt*16 + quad*4 + i;
            if (row < NB && cntN[row] > 0) rmask |= 1u << (mt*4 + i);
        }

    // S fragments (constant across rounds)
    bf8 sh[2], sl[2];
    #pragma unroll
    for (int mo = 0; mo < 2; ++mo) {
        sh[mo] = *(const bf8*)&Shi[(mo*16 + l16)*SS + quad*8];
        sl[mo] = *(const bf8*)&Slo[(mo*16 + l16)*SS + quad*8];
    }
    const int srcbase = ((quad & 1) << 5) | l16;
    const int mtsel   = quad >> 1;

    // ---- 3 message-passing rounds ----
    for (int r = 0; r < 3; ++r) {
        const u16* Wsw = WtAll + (size_t)r*131072;

        f4 C1[2][4], P[2][4];
        #pragma unroll
        for (int mt = 0; mt < 2; ++mt)
            #pragma unroll
            for (int nt = 0; nt < 4; ++nt) {
                C1[mt][nt] = (f4){0.f, 0.f, 0.f, 0.f};
                P [mt][nt] = (f4){0.f, 0.f, 0.f, 0.f};
            }

        #pragma unroll
        for (int kt = 0; kt < 8; ++kt) {
            bf8 ah[2];
            #pragma unroll
            for (int mt = 0; mt < 2; ++mt)
                ah[mt] = *(const bf8*)&Ahi[(mt*16 + l16)*SA + kt*32 + quad*8];
            #pragma unroll
            for (int nt = 0; nt < 4; ++nt) {
                // fully coalesced fragment loads (1 KB contiguous per instr)
                const bf8 bt = *(const bf8*)&Wsw[(size_t)(((wave*16 + kt  )*4 + nt))*512 + lane*8];
                const bf8 bb = *(const bf8*)&Wsw[(size_t)(((wave*16 + kt+8)*4 + nt))*512 + lane*8];
                #pragma unroll
                for (int mt = 0; mt < 2; ++mt) {
                    C1[mt][nt] = __builtin_amdgcn_mfma_f32_16x16x32_bf16(ah[mt], bt, C1[mt][nt], 0, 0, 0);
                    P [mt][nt] = __builtin_amdgcn_mfma_f32_16x16x32_bf16(ah[mt], bb, P [mt][nt], 0, 0, 0);
                }
            }
        }

        // pack P to bf16 pairs
        unsigned pk[2][4][2];
        #pragma unroll
        for (int mt = 0; mt < 2; ++mt)
            #pragma unroll
            for (int nt = 0; nt < 4; ++nt) {
                pk[mt][nt][0] = (u32)f2us(P[mt][nt][0]) | ((u32)f2us(P[mt][nt][1]) << 16);
                pk[mt][nt][1] = (u32)f2us(P[mt][nt][2]) | ((u32)f2us(P[mt][nt][3]) << 16);
            }

        // C1 += S @ P (B-frags in-register via shfl)
        #pragma unroll
        for (int nt = 0; nt < 4; ++nt) {
            union { bf8 v; u32 u[4]; } bf_;
            #pragma unroll
            for (int t2 = 0; t2 < 4; ++t2) {
                const int src = srcbase + ((t2 >> 1) << 4);
                const u32 v0 = __shfl(pk[0][nt][t2 & 1], src, 64);
                const u32 v1 = __shfl(pk[1][nt][t2 & 1], src, 64);
                bf_.u[t2] = mtsel ? v1 : v0;
            }
            #pragma unroll
            for (int mo = 0; mo < 2; ++mo) {
                C1[mo][nt] = __builtin_amdgcn_mfma_f32_16x16x32_bf16(sh[mo], bf_.v, C1[mo][nt], 0, 0, 0);
                C1[mo][nt] = __builtin_amdgcn_mfma_f32_16x16x32_bf16(sl[mo], bf_.v, C1[mo][nt], 0, 0, 0);
            }
        }
        __syncthreads();

        // epilogue
        const float* br = (r == 0) ? bmp1 : ((r == 1) ? bmp2 : bmp3);
        #pragma unroll
        for (int nt = 0; nt < 4; ++nt) {
            const int col = wave*64 + nt*16 + l16;
            const float bias = br[col];
            float cmax = 0.f;
            #pragma unroll
            for (int mt = 0; mt < 2; ++mt)
                #pragma unroll
                for (int i = 0; i < 4; ++i) {
                    const int row = mt*16 + quad*4 + i;
                    float v = fmaxf(C1[mt][nt][i] + bias, 0.f);
                    if (!((rmask >> (mt*4 + i)) & 1u)) v = 0.f;
                    Ahi[row*SA + col] = (short)f2us(v);
                    cmax = fmaxf(cmax, v);
                }
            cmax = fmaxf(cmax, __shfl_xor(cmax, 16, 64));
            cmax = fmaxf(cmax, __shfl_xor(cmax, 32, 64));
            if (quad == 0)
                G[(size_t)g*1024 + (r+1)*256 + col] = f2us(cmax);
        }
        __syncthreads();
    }
}

// ---------------------------------------------------------------------------
// Heads: 256 blocks x 8 graphs (M=8 dup to 16). W reads coalesced.
// ---------------------------------------------------------------------------
__global__ __launch_bounds__(256, 4) void head_kernel(
    const char* __restrict__ ws, const u16* __restrict__ G,
    const float* __restrict__ bagg, const float* __restrict__ bmu,
    const float* __restrict__ bvar, float* __restrict__ out)
{
    __shared__ __align__(16) short Gs[8*SG];     // 16512 B
    __shared__ __align__(16) short Lhi[16*SL];
    __shared__ __align__(16) short Llo[16*SL];

    const int tid  = threadIdx.x;
    const int wave = tid >> 6, lane = tid & 63;
    const int l16  = lane & 15, quad = lane >> 4;
    const int g0   = blockIdx.x * 8;

    const u16* WtA = (const u16*)(ws + WOFF_WAGG);
    const u16* WtM = (const u16*)(ws + WOFF_WMU);
    const u16* WtV = (const u16*)(ws + WOFF_WVAR);

    // stage 8 G rows (coalesced)
    #pragma unroll
    for (int rr = 0; rr < 8; ++rr) {
        ((u32*)&Gs[rr*SG])[tid]       = ((const u32*)&G[(size_t)(g0+rr)*1024])[tid];
        ((u32*)&Gs[rr*SG])[tid + 256] = ((const u32*)&G[(size_t)(g0+rr)*1024])[tid + 256];
    }
    __syncthreads();

    // GEMM1: latent[8][256] = G[8][1024] @ Wagg
    f4 acc[4];
    #pragma unroll
    for (int nt = 0; nt < 4; ++nt) acc[nt] = (f4){0.f, 0.f, 0.f, 0.f};

    #pragma unroll 8
    for (int kt = 0; kt < 32; ++kt) {
        const bf8 ah = *(const bf8*)&Gs[(l16 & 7)*SG + kt*32 + quad*8];
        #pragma unroll
        for (int nt = 0; nt < 4; ++nt) {
            const bf8 b = *(const bf8*)&WtA[(size_t)((wave*32 + kt)*4 + nt)*512 + lane*8];
            acc[nt] = __builtin_amdgcn_mfma_f32_16x16x32_bf16(ah, b, acc[nt], 0, 0, 0);
        }
    }
    #pragma unroll
    for (int nt = 0; nt < 4; ++nt) {
        const int col = wave*64 + nt*16 + l16;
        const float bias = bagg[col];
        #pragma unroll
        for (int i = 0; i < 4; ++i) {
            const int row = quad*4 + i;     // rows 8..15 duplicate 0..7
            const float v = acc[nt][i] + bias;
            const u16 hi = f2us(v);
            Lhi[row*SL + col] = (short)hi;
            Llo[row*SL + col] = (short)f2us(v - us2f(hi));
        }
    }
    __syncthreads();

    // GEMM2: mu / log_var
    f4 am[4], av[4];
    #pragma unroll
    for (int nt = 0; nt < 4; ++nt) {
        am[nt] = (f4){0.f, 0.f, 0.f, 0.f};
        av[nt] = (f4){0.f, 0.f, 0.f, 0.f};
    }
    #pragma unroll
    for (int kt = 0; kt < 8; ++kt) {
        const bf8 ah = *(const bf8*)&Lhi[l16*SL + kt*32 + quad*8];
        const bf8 al = *(const bf8*)&Llo[l16*SL + kt*32 + quad*8];
        #pragma unroll
        for (int nt = 0; nt < 4; ++nt) {
            const bf8 bm_ = *(const bf8*)&WtM[(size_t)((wave*8 + kt)*4 + nt)*512 + lane*8];
            const bf8 bv_ = *(const bf8*)&WtV[(size_t)((wave*8 + kt)*4 + nt)*512 + lane*8];
            am[nt] = __builtin_amdgcn_mfma_f32_16x16x32_bf16(ah, bm_, am[nt], 0, 0, 0);
            am[nt] = __builtin_amdgcn_mfma_f32_16x16x32_bf16(al, bm_, am[nt], 0, 0, 0);
            av[nt] = __builtin_amdgcn_mfma_f32_16x16x32_bf16(ah, bv_, av[nt], 0, 0, 0);
            av[nt] = __builtin_amdgcn_mfma_f32_16x16x32_bf16(al, bv_, av[nt], 0, 0, 0);
        }
    }
    #pragma unroll
    for (int nt = 0; nt < 4; ++nt) {
        const int col = wave*64 + nt*16 + l16;
        const float b1 = bmu[col], b2 = bvar[col];
        #pragma unroll
        for (int i = 0; i < 4; ++i) {
            const int r = quad*4 + i;
            if (r < 8) {
                const int row = g0 + r;
                out[(size_t)row*256 + col]          = am[nt][i] + b1;
                out[524288 + (size_t)row*256 + col] = av[nt][i] + b2;
            }
        }
    }
}

extern "C" void kernel_launch(void* const* d_in, const int* in_sizes, int n_in,
                              void* d_out, int out_size, void* d_ws, size_t ws_size,
                              hipStream_t stream)
{
    const float* geometry  = (const float*)d_in[0];
    const void*  semantic  = d_in[1];
    const void*  edge_ix   = d_in[2];
    const float* W_geo = (const float*)d_in[4];
    const float* b_geo = (const float*)d_in[5];
    const float* emb   = (const float*)d_in[6];
    const float* W_lot = (const float*)d_in[7];
    const float* b_lot = (const float*)d_in[8];
    const float* Wmp1  = (const float*)d_in[9];
    const float* bmp1  = (const float*)d_in[10];
    const float* Wmp2  = (const float*)d_in[11];
    const float* bmp2  = (const float*)d_in[12];
    const float* Wmp3  = (const float*)d_in[13];
    const float* bmp3  = (const float*)d_in[14];
    const float* Wagg  = (const float*)d_in[15];
    const float* bagg  = (const float*)d_in[16];
    const float* Wmu   = (const float*)d_in[17];
    const float* bmu   = (const float*)d_in[18];
    const float* Wvar  = (const float*)d_in[19];
    const float* bvar  = (const float*)d_in[20];

    char* ws    = (char*)d_ws;
    int*  flags = (int*)(ws + WOFF_FLAG);
    u16*  G     = (u16*)(ws + WOFF_G);

    prep_kernel<<<210, 256, 0, stream>>>(Wmp1, Wmp2, Wmp3, Wagg, Wmu, Wvar,
                                         W_geo, b_geo, emb, W_lot, b_lot,
                                         edge_ix, semantic, ws, flags);
    graph_kernel<<<BG, 256, 0, stream>>>(geometry, semantic, edge_ix,
                                         bmp1, bmp2, bmp3, ws, G, flags);
    head_kernel<<<256, 256, 0, stream>>>(ws, G, bagg, bmu, bvar, (float*)d_out);
}

// Round 12
// 237.151 us; speedup vs baseline: 2.8530x; 1.3320x over previous
//
#include <hip/hip_runtime.h>

typedef unsigned short u16;
typedef unsigned int u32;
typedef __attribute__((ext_vector_type(8))) short bf8;   // 8 bf16 (4 VGPRs)
typedef __attribute__((ext_vector_type(4))) float f4;    // MFMA C/D frag
typedef __attribute__((ext_vector_type(4))) int i4;

#define NB  30
#define BG  2048
#define EPG 240
#define NEg (BG*EPG)
#define SA  260     // A row stride (shorts): 130 dw -> 2*row mod 32, uniform 2-way
#define SS  40      // S row stride
#define SL  264     // latent row stride (heads)
#define SG  1032    // head G-stage row stride (shorts)

// workspace offsets (bytes). W tensors stored fragment-major (swizzled):
// chunk(wave,ktf,nt) = ((wave*(K/32)+ktf)*4+nt)*512 u16, elem = lane*8+j,
// value = W^T[wave*64+nt*16+(lane&15)][ktf*32+(lane>>4)*8+j]
#define WOFF_WT    0                         // [3][256][512] bf16
#define WOFF_WAGG  786432                    // [256][1024] bf16
#define WOFF_WMU   (786432+524288)           // [256][256] bf16
#define WOFF_WVAR  (786432+524288+131072)
#define WOFF_TAB   (786432+524288+262144)    // fp32 tables: 12032 floats
#define WOFF_G     (WOFF_TAB + 48128)        // g bf16 [2048][1024]
#define WOFF_FLAG  (WOFF_G + 4194304)        // 2 ints

__device__ __forceinline__ float us2f(u16 u) {
    union { u32 i; float f; } v; v.i = ((u32)u) << 16; return v.f;
}
__device__ __forceinline__ u16 f2us(float f) {
    union { float f; u32 u; } v; v.f = f;
    u32 u = v.u;
    return (u16)((u + 0x7FFFu + ((u >> 16) & 1u)) >> 16);   // RNE
}
__device__ __forceinline__ int ldidx(const void* p, long long i, int i64) {
    return i64 ? (int)((const long long*)p)[i] : ((const int*)p)[i];
}

// ---------------------------------------------------------------------------
// Prep (210 blocks): 64x64 tile loads -> swizzled fragment-major bf16 writes,
// fp32 encoder tables (192..208), dtype probe (209).
// ---------------------------------------------------------------------------
__global__ __launch_bounds__(256) void prep_kernel(
    const float* __restrict__ Wmp1, const float* __restrict__ Wmp2,
    const float* __restrict__ Wmp3, const float* __restrict__ Wagg,
    const float* __restrict__ Wmu,  const float* __restrict__ Wvar,
    const float* __restrict__ W_geo, const float* __restrict__ b_geo,
    const float* __restrict__ emb,   const float* __restrict__ W_lot,
    const float* __restrict__ b_lot,
    const void* __restrict__ edge,  const void* __restrict__ semA,
    char* __restrict__ ws, int* __restrict__ flags)
{
    const int t = threadIdx.x;
    const int b = blockIdx.x;

    if (b == 209) {                    // probe
        if (t == 0) {
            const int* e32 = (const int*)edge;
            int zc = 0;
            for (int j = 1; j <= 31; j += 2) if (e32[j] == 0) zc++;
            flags[0] = (zc == 16) ? 1 : 0;
            flags[1] = 0;
        }
        return;
    }

    if (b >= 192) {                    // tables (exact fp32 algebra)
        float* tab = (float*)(ws + WOFF_TAB);
        const int d = t, b2 = b - 192;
        if (b2 < 5) {
            float a = 0.f;
            #pragma unroll 8
            for (int k = 0; k < 256; ++k)
                a = fmaf(W_geo[b2*256 + k], W_lot[k*256 + d], a);
            tab[b2*256 + d] = a;
        } else if (b2 < 16) {
            const int s = b2 - 5;
            float a = 0.f;
            #pragma unroll 8
            for (int k = 0; k < 256; ++k)
                a = fmaf(emb[s*256 + k], W_lot[(256 + k)*256 + d], a);
            tab[1536 + s*256 + d] = a;
        } else {
            float a = b_lot[d];
            #pragma unroll 8
            for (int k = 0; k < 256; ++k)
                a = fmaf(b_geo[k], W_lot[k*256 + d], a);
            tab[1280 + d] = a;
            for (int p = 0; p < NB; ++p)
                tab[4352 + p*256 + d] = W_lot[(512 + p)*256 + d];
        }
        return;
    }

    // 64x64 tile: W[K][256] fp32 -> swizzled bf16 chunks
    __shared__ short tile[64 * 65];
    const float* W; u16* Wt; int K32, bk, bn;
    if (b < 96)       { const int r = b/32, tt = b%32;
                        W = (r==0)?Wmp1:((r==1)?Wmp2:Wmp3);
                        Wt = (u16*)(ws + WOFF_WT) + (size_t)r*256*512;
                        K32 = 16;  bk = tt/4;  bn = tt%4; }
    else if (b < 160) { const int tt = b-96;
                        W = Wagg; Wt = (u16*)(ws + WOFF_WAGG);
                        K32 = 32; bk = tt/4;  bn = tt%4; }
    else if (b < 176) { const int tt = b-160;
                        W = Wmu;  Wt = (u16*)(ws + WOFF_WMU);
                        K32 = 8;  bk = tt/4;  bn = tt%4; }
    else              { const int tt = b-176;
                        W = Wvar; Wt = (u16*)(ws + WOFF_WVAR);
                        K32 = 8;  bk = tt/4;  bn = tt%4; }

    const int r = t >> 6, c = t & 63;
    const int k0 = bk*64, n0 = bn*64;
    #pragma unroll
    for (int i = 0; i < 16; ++i) {
        const int kk = r + i*4;
        tile[kk*65 + c] = (short)f2us(W[(size_t)(k0 + kk)*256 + n0 + c]);
    }
    __syncthreads();

    // write 8 chunks (dk x nt), each 1 KB contiguous
    const int lane = t >> 2;
    const int j0   = (t & 3) * 2;
    const int quad = lane >> 4, l16 = lane & 15;
    #pragma unroll
    for (int dk = 0; dk < 2; ++dk) {
        const int ktf = bk*2 + dk;
        #pragma unroll
        for (int nt = 0; nt < 4; ++nt) {
            const int chunk = (bn*K32 + ktf)*4 + nt;
            u32* dst = (u32*)(Wt + (size_t)chunk*512);
            const int kl = dk*32 + quad*8 + j0;
            const int nl = nt*16 + l16;
            const u32 v = (u32)(u16)tile[kl*65 + nl] |
                          ((u32)(u16)tile[(kl+1)*65 + nl] << 16);
            dst[t] = v;
        }
    }
}

// ---------------------------------------------------------------------------
// Graph kernel: one block per graph, 4 waves. W reads fully coalesced
// (fragment-major). cntC overlays Ahi rows 0..7 (barrier-separated).
// __launch_bounds__(256,4): 4 waves/SIMD cap -> VGPR 64 + AGPR accs, no spill
// (R11's (256,5) forced VGPR=48 -> 338 MB scratch spill traffic, HBM-bound).
// ---------------------------------------------------------------------------
__global__ __launch_bounds__(256, 4) void graph_kernel(
    const float* __restrict__ geometry,
    const void* __restrict__ semantic,
    const void* __restrict__ edge_index,
    const float* __restrict__ bmp1, const float* __restrict__ bmp2,
    const float* __restrict__ bmp3,
    const char* __restrict__ ws, u16* __restrict__ G,
    const int* __restrict__ flags)
{
    __shared__ __align__(16) short Ahi[32*SA];   // 16640 B (rows 0..7 alias cntC)
    __shared__ __align__(16) short Shi[32*SS];   // 2560 B
    __shared__ __align__(16) short Slo[32*SS];   // 2560 B
    __shared__ int   cntN[32];
    __shared__ float geo_l[NB*5];
    __shared__ int   sem_l[NB];

    int* cntC = (int*)Ahi;                       // 4096 B overlay

    const int tid  = threadIdx.x;
    const int g    = blockIdx.x;
    const int wave = tid >> 6, lane = tid & 63;
    const int l16  = lane & 15, quad = lane >> 4;

    const int i64 = flags[0];
    const u16* WtAll = (const u16*)(ws + WOFF_WT);
    const float* tab = (const float*)(ws + WOFF_TAB);

    // ---- zero / stage ----
    {
        i4 z = {0, 0, 0, 0};
        ((i4*)cntC)[tid] = z;                                 // 4096 B
        if (tid < 65) ((i4*)&Ahi[30*SA])[tid] = z;            // rows 30,31 (1040 B)
        if (tid < 160) { ((i4*)Shi)[tid] = z; ((i4*)Slo)[tid] = z; }
        if (tid < 32) cntN[tid] = 0;
        if (tid < NB*5) geo_l[tid] = geometry[(size_t)g*NB*5 + tid];
        if (tid < NB)   sem_l[tid] = ldidx(semantic, g*NB + tid, i64);
    }
    __syncthreads();

    // ---- edge counts ----
    if (tid < EPG) {
        const long long e = (long long)g*EPG + tid;
        const int s  = ldidx(edge_index, e,                  i64) - g*NB;
        const int dd = ldidx(edge_index, (long long)NEg + e, i64) - g*NB;
        atomicAdd(&cntC[dd*32 + s], 1);
        atomicAdd(&cntN[dd], 1);
    }
    __syncthreads();

    // ---- S = cnt_nm / cnt_n, exact hi/lo split ----
    for (int i = tid; i < 960; i += 256) {
        const int n = i >> 5, m = i & 31;
        const int c = cntC[n*32 + m], cn = cntN[n];
        const float v = (cn > 0) ? (float)c / (float)cn : 0.f;
        const u16 hi = f2us(v);
        Shi[n*SS + m] = (short)hi;
        Slo[n*SS + m] = (short)f2us(v - us2f(hi));
    }
    __syncthreads();   // cntC reads done before encoder overwrites rows 0..7

    // ---- encoder via exact tables; thread = col d ----
    {
        const int d = tid;
        const float m0 = tab[0*256+d], m1 = tab[1*256+d], m2 = tab[2*256+d],
                    m3 = tab[3*256+d], m4 = tab[4*256+d];
        const float cD = tab[1280 + d];
        float gmax = 0.f;
        for (int n = 0; n < NB; ++n) {
            const int s = sem_l[n];
            float a = cD + tab[1536 + s*256 + d] + tab[4352 + n*256 + d];
            a = fmaf(geo_l[n*5+0], m0, a); a = fmaf(geo_l[n*5+1], m1, a);
            a = fmaf(geo_l[n*5+2], m2, a); a = fmaf(geo_l[n*5+3], m3, a);
            a = fmaf(geo_l[n*5+4], m4, a);
            const float v = fmaxf(a, 0.f);
            Ahi[n*SA + d] = (short)f2us(v);
            gmax = fmaxf(gmax, v);
        }
        G[(size_t)g*1024 + d] = f2us(gmax);   // g0
    }
    __syncthreads();

    // ---- per-lane row mask ----
    unsigned rmask = 0;
    #pragma unroll
    for (int mt = 0; mt < 2; ++mt)
        #pragma unroll
        for (int i = 0; i < 4; ++i) {
            const int row = mt*16 + quad*4 + i;
            if (row < NB && cntN[row] > 0) rmask |= 1u << (mt*4 + i);
        }

    // S fragments (constant across rounds)
    bf8 sh[2], sl[2];
    #pragma unroll
    for (int mo = 0; mo < 2; ++mo) {
        sh[mo] = *(const bf8*)&Shi[(mo*16 + l16)*SS + quad*8];
        sl[mo] = *(const bf8*)&Slo[(mo*16 + l16)*SS + quad*8];
    }
    const int srcbase = ((quad & 1) << 5) | l16;
    const int mtsel   = quad >> 1;

    // ---- 3 message-passing rounds ----
    for (int r = 0; r < 3; ++r) {
        const u16* Wsw = WtAll + (size_t)r*131072;

        f4 C1[2][4], P[2][4];
        #pragma unroll
        for (int mt = 0; mt < 2; ++mt)
            #pragma unroll
            for (int nt = 0; nt < 4; ++nt) {
                C1[mt][nt] = (f4){0.f, 0.f, 0.f, 0.f};
                P [mt][nt] = (f4){0.f, 0.f, 0.f, 0.f};
            }

        #pragma unroll
        for (int kt = 0; kt < 8; ++kt) {
            bf8 ah[2];
            #pragma unroll
            for (int mt = 0; mt < 2; ++mt)
                ah[mt] = *(const bf8*)&Ahi[(mt*16 + l16)*SA + kt*32 + quad*8];
            #pragma unroll
            for (int nt = 0; nt < 4; ++nt) {
                // fully coalesced fragment loads (1 KB contiguous per instr)
                const bf8 bt = *(const bf8*)&Wsw[(size_t)(((wave*16 + kt  )*4 + nt))*512 + lane*8];
                const bf8 bb = *(const bf8*)&Wsw[(size_t)(((wave*16 + kt+8)*4 + nt))*512 + lane*8];
                #pragma unroll
                for (int mt = 0; mt < 2; ++mt) {
                    C1[mt][nt] = __builtin_amdgcn_mfma_f32_16x16x32_bf16(ah[mt], bt, C1[mt][nt], 0, 0, 0);
                    P [mt][nt] = __builtin_amdgcn_mfma_f32_16x16x32_bf16(ah[mt], bb, P [mt][nt], 0, 0, 0);
                }
            }
        }

        // pack P to bf16 pairs
        unsigned pk[2][4][2];
        #pragma unroll
        for (int mt = 0; mt < 2; ++mt)
            #pragma unroll
            for (int nt = 0; nt < 4; ++nt) {
                pk[mt][nt][0] = (u32)f2us(P[mt][nt][0]) | ((u32)f2us(P[mt][nt][1]) << 16);
                pk[mt][nt][1] = (u32)f2us(P[mt][nt][2]) | ((u32)f2us(P[mt][nt][3]) << 16);
            }

        // C1 += S @ P (B-frags in-register via shfl)
        #pragma unroll
        for (int nt = 0; nt < 4; ++nt) {
            union { bf8 v; u32 u[4]; } bf_;
            #pragma unroll
            for (int t2 = 0; t2 < 4; ++t2) {
                const int src = srcbase + ((t2 >> 1) << 4);
                const u32 v0 = __shfl(pk[0][nt][t2 & 1], src, 64);
                const u32 v1 = __shfl(pk[1][nt][t2 & 1], src, 64);
                bf_.u[t2] = mtsel ? v1 : v0;
            }
            #pragma unroll
            for (int mo = 0; mo < 2; ++mo) {
                C1[mo][nt] = __builtin_amdgcn_mfma_f32_16x16x32_bf16(sh[mo], bf_.v, C1[mo][nt], 0, 0, 0);
                C1[mo][nt] = __builtin_amdgcn_mfma_f32_16x16x32_bf16(sl[mo], bf_.v, C1[mo][nt], 0, 0, 0);
            }
        }
        __syncthreads();

        // epilogue
        const float* br = (r == 0) ? bmp1 : ((r == 1) ? bmp2 : bmp3);
        #pragma unroll
        for (int nt = 0; nt < 4; ++nt) {
            const int col = wave*64 + nt*16 + l16;
            const float bias = br[col];
            float cmax = 0.f;
            #pragma unroll
            for (int mt = 0; mt < 2; ++mt)
                #pragma unroll
                for (int i = 0; i < 4; ++i) {
                    const int row = mt*16 + quad*4 + i;
                    float v = fmaxf(C1[mt][nt][i] + bias, 0.f);
                    if (!((rmask >> (mt*4 + i)) & 1u)) v = 0.f;
                    Ahi[row*SA + col] = (short)f2us(v);
                    cmax = fmaxf(cmax, v);
                }
            cmax = fmaxf(cmax, __shfl_xor(cmax, 16, 64));
            cmax = fmaxf(cmax, __shfl_xor(cmax, 32, 64));
            if (quad == 0)
                G[(size_t)g*1024 + (r+1)*256 + col] = f2us(cmax);
        }
        __syncthreads();
    }
}

// ---------------------------------------------------------------------------
// Heads: 256 blocks x 8 graphs (M=8 dup to 16). W reads coalesced.
// ---------------------------------------------------------------------------
__global__ __launch_bounds__(256, 4) void head_kernel(
    const char* __restrict__ ws, const u16* __restrict__ G,
    const float* __restrict__ bagg, const float* __restrict__ bmu,
    const float* __restrict__ bvar, float* __restrict__ out)
{
    __shared__ __align__(16) short Gs[8*SG];     // 16512 B
    __shared__ __align__(16) short Lhi[16*SL];
    __shared__ __align__(16) short Llo[16*SL];

    const int tid  = threadIdx.x;
    const int wave = tid >> 6, lane = tid & 63;
    const int l16  = lane & 15, quad = lane >> 4;
    const int g0   = blockIdx.x * 8;

    const u16* WtA = (const u16*)(ws + WOFF_WAGG);
    const u16* WtM = (const u16*)(ws + WOFF_WMU);
    const u16* WtV = (const u16*)(ws + WOFF_WVAR);

    // stage 8 G rows (coalesced)
    #pragma unroll
    for (int rr = 0; rr < 8; ++rr) {
        ((u32*)&Gs[rr*SG])[tid]       = ((const u32*)&G[(size_t)(g0+rr)*1024])[tid];
        ((u32*)&Gs[rr*SG])[tid + 256] = ((const u32*)&G[(size_t)(g0+rr)*1024])[tid + 256];
    }
    __syncthreads();

    // GEMM1: latent[8][256] = G[8][1024] @ Wagg
    f4 acc[4];
    #pragma unroll
    for (int nt = 0; nt < 4; ++nt) acc[nt] = (f4){0.f, 0.f, 0.f, 0.f};

    #pragma unroll 8
    for (int kt = 0; kt < 32; ++kt) {
        const bf8 ah = *(const bf8*)&Gs[(l16 & 7)*SG + kt*32 + quad*8];
        #pragma unroll
        for (int nt = 0; nt < 4; ++nt) {
            const bf8 b = *(const bf8*)&WtA[(size_t)((wave*32 + kt)*4 + nt)*512 + lane*8];
            acc[nt] = __builtin_amdgcn_mfma_f32_16x16x32_bf16(ah, b, acc[nt], 0, 0, 0);
        }
    }
    #pragma unroll
    for (int nt = 0; nt < 4; ++nt) {
        const int col = wave*64 + nt*16 + l16;
        const float bias = bagg[col];
        #pragma unroll
        for (int i = 0; i < 4; ++i) {
            const int row = quad*4 + i;     // rows 8..15 duplicate 0..7
            const float v = acc[nt][i] + bias;
            const u16 hi = f2us(v);
            Lhi[row*SL + col] = (short)hi;
            Llo[row*SL + col] = (short)f2us(v - us2f(hi));
        }
    }
    __syncthreads();

    // GEMM2: mu / log_var
    f4 am[4], av[4];
    #pragma unroll
    for (int nt = 0; nt < 4; ++nt) {
        am[nt] = (f4){0.f, 0.f, 0.f, 0.f};
        av[nt] = (f4){0.f, 0.f, 0.f, 0.f};
    }
    #pragma unroll
    for (int kt = 0; kt < 8; ++kt) {
        const bf8 ah = *(const bf8*)&Lhi[l16*SL + kt*32 + quad*8];
        const bf8 al = *(const bf8*)&Llo[l16*SL + kt*32 + quad*8];
        #pragma unroll
        for (int nt = 0; nt < 4; ++nt) {
            const bf8 bm_ = *(const bf8*)&WtM[(size_t)((wave*8 + kt)*4 + nt)*512 + lane*8];
            const bf8 bv_ = *(const bf8*)&WtV[(size_t)((wave*8 + kt)*4 + nt)*512 + lane*8];
            am[nt] = __builtin_amdgcn_mfma_f32_16x16x32_bf16(ah, bm_, am[nt], 0, 0, 0);
            am[nt] = __builtin_amdgcn_mfma_f32_16x16x32_bf16(al, bm_, am[nt], 0, 0, 0);
            av[nt] = __builtin_amdgcn_mfma_f32_16x16x32_bf16(ah, bv_, av[nt], 0, 0, 0);
            av[nt] = __builtin_amdgcn_mfma_f32_16x16x32_bf16(al, bv_, av[nt], 0, 0, 0);
        }
    }
    #pragma unroll
    for (int nt = 0; nt < 4; ++nt) {
        const int col = wave*64 + nt*16 + l16;
        const float b1 = bmu[col], b2 = bvar[col];
        #pragma unroll
        for (int i = 0; i < 4; ++i) {
            const int r = quad*4 + i;
            if (r < 8) {
                const int row = g0 + r;
                out[(size_t)row*256 + col]          = am[nt][i] + b1;
                out[524288 + (size_t)row*256 + col] = av[nt][i] + b2;
            }
        }
    }
}

extern "C" void kernel_launch(void* const* d_in, const int* in_sizes, int n_in,
                              void* d_out, int out_size, void* d_ws, size_t ws_size,
                              hipStream_t stream)
{
    const float* geometry  = (const float*)d_in[0];
    const void*  semantic  = d_in[1];
    const void*  edge_ix   = d_in[2];
    const float* W_geo = (const float*)d_in[4];
    const float* b_geo = (const float*)d_in[5];
    const float* emb   = (const float*)d_in[6];
    const float* W_lot = (const float*)d_in[7];
    const float* b_lot = (const float*)d_in[8];
    const float* Wmp1  = (const float*)d_in[9];
    const float* bmp1  = (const float*)d_in[10];
    const float* Wmp2  = (const float*)d_in[11];
    const float* bmp2  = (const float*)d_in[12];
    const float* Wmp3  = (const float*)d_in[13];
    const float* bmp3  = (const float*)d_in[14];
    const float* Wagg  = (const float*)d_in[15];
    const float* bagg  = (const float*)d_in[16];
    const float* Wmu   = (const float*)d_in[17];
    const float* bmu   = (const float*)d_in[18];
    const float* Wvar  = (const float*)d_in[19];
    const float* bvar  = (const float*)d_in[20];

    char* ws    = (char*)d_ws;
    int*  flags = (int*)(ws + WOFF_FLAG);
    u16*  G     = (u16*)(ws + WOFF_G);

    prep_kernel<<<210, 256, 0, stream>>>(Wmp1, Wmp2, Wmp3, Wagg, Wmu, Wvar,
                                         W_geo, b_geo, emb, W_lot, b_lot,
                                         edge_ix, semantic, ws, flags);
    graph_kernel<<<BG, 256, 0, stream>>>(geometry, semantic, edge_ix,
                                         bmp1, bmp2, bmp3, ws, G, flags);
    head_kernel<<<256, 256, 0, stream>>>(ws, G, bagg, bmu, bvar, (float*)d_out);
}